// Round 2
// baseline (1258.607 us; speedup 1.0000x reference)
//
#include <hip/hip_runtime.h>
#include <hip/hip_bf16.h>

// Problem: AdvancedAttentionLayer  B=2, S=2048, D=1024, H=16, DH=64
// Round 2: fp32 inputs/outputs (per reference dtypes), fp32 compute,
// bf16 workspace intermediates. Vector (non-MFMA), correctness-first.

#define B_  2
#define S_  2048
#define D_  1024
#define H_  16
#define DH_ 64
#define BS_ (B_*S_)

typedef __hip_bfloat16 bf16;

__device__ __forceinline__ float b2f(bf16 x) { return __bfloat162float(x); }
__device__ __forceinline__ bf16  f2b(float x) { return __float2bfloat16(x); }

// ---------------------------------------------------------------------------
// Kernel 1: fused QKV projection.  Y = X @ W + bias (+ emotion bias for q)
// X,W,bias fp32; output bf16 in ws, layout [B,H,S,DH].
// Grid: (BS/64, D/64, 3)  Block: 256 (16x16 threads, 4x4 micro-tile each)
// ---------------------------------------------------------------------------
__global__ __launch_bounds__(256) void proj_qkv_kernel(
    const float* __restrict__ X,
    const float* __restrict__ Wq, const float* __restrict__ bq,
    const float* __restrict__ Wk, const float* __restrict__ bk,
    const float* __restrict__ Wv, const float* __restrict__ bv,
    const float* __restrict__ emo,   // [H*DH] flat == indexed by output col n
    bf16* __restrict__ q_ws, bf16* __restrict__ k_ws, bf16* __restrict__ v_ws)
{
    const int m0 = blockIdx.x * 64;
    const int n0 = blockIdx.y * 64;
    const int z  = blockIdx.z;

    const float* __restrict__ W    = (z == 0) ? Wq : (z == 1) ? Wk : Wv;
    const float* __restrict__ bias = (z == 0) ? bq : (z == 1) ? bk : bv;
    bf16* __restrict__ out         = (z == 0) ? q_ws : (z == 1) ? k_ws : v_ws;

    __shared__ float Xs[16][68];   // k-major: Xs[kk][row]
    __shared__ float Ws[16][64];   // k-major: Ws[kk][col]

    const int t  = threadIdx.x;
    const int ty = t >> 4, tx = t & 15;
    const int r0 = ty * 4, c0 = tx * 4;

    // staging indices
    const int xr = t >> 2;          // 0..63 row in X tile
    const int xk = (t & 3) * 4;     // k offset
    const int wk = t >> 4;          // 0..15 k row in W tile
    const int wc = (t & 15) * 4;    // col offset

    float acc[4][4] = {};

    for (int kb = 0; kb < D_; kb += 16) {
        {
            const float4 xv = *(const float4*)(X + (size_t)(m0 + xr) * D_ + kb + xk);
            Xs[xk + 0][xr] = xv.x;
            Xs[xk + 1][xr] = xv.y;
            Xs[xk + 2][xr] = xv.z;
            Xs[xk + 3][xr] = xv.w;
        }
        {
            const float4 wv = *(const float4*)(W + (size_t)(kb + wk) * D_ + n0 + wc);
            Ws[wk][wc + 0] = wv.x;
            Ws[wk][wc + 1] = wv.y;
            Ws[wk][wc + 2] = wv.z;
            Ws[wk][wc + 3] = wv.w;
        }
        __syncthreads();
        #pragma unroll
        for (int kk = 0; kk < 16; kk++) {
            float a[4], bb[4];
            #pragma unroll
            for (int i = 0; i < 4; i++) a[i]  = Xs[kk][r0 + i];
            #pragma unroll
            for (int j = 0; j < 4; j++) bb[j] = Ws[kk][c0 + j];
            #pragma unroll
            for (int i = 0; i < 4; i++)
                #pragma unroll
                for (int j = 0; j < 4; j++)
                    acc[i][j] = fmaf(a[i], bb[j], acc[i][j]);
        }
        __syncthreads();
    }

    const int h = n0 >> 6;   // n0 is a multiple of 64 -> head fixed per block
    #pragma unroll
    for (int j = 0; j < 4; j++) {
        const int n   = n0 + c0 + j;
        const int dh  = n & 63;
        const float bv_ = bias[n];
        const float ev  = (z == 0) ? emo[n] : 0.0f;
        #pragma unroll
        for (int i = 0; i < 4; i++) {
            const int m = m0 + r0 + i;
            const int b = m >> 11, s = m & 2047;
            const float y = acc[i][j] + bv_ + ev;
            out[(((size_t)(b * H_ + h) * S_) + s) * DH_ + dh] = f2b(y);
        }
    }
}

// ---------------------------------------------------------------------------
// Kernel 2: flash-style attention with key-padding mask.
// Grid: (B*H, S/64)  Block: 256. One block = one (b,h) x 64-query tile.
// q pre-scaled by 1/sqrt(DH)=0.125 at load. Context written [B,S,D] bf16 ws.
// ---------------------------------------------------------------------------
__global__ __launch_bounds__(256) void attn_kernel(
    const bf16* __restrict__ q_ws, const bf16* __restrict__ k_ws,
    const bf16* __restrict__ v_ws, const int* __restrict__ mask,
    bf16* __restrict__ ctx)
{
    const int bh = blockIdx.x;          // 0..31
    const int q0 = blockIdx.y * 64;
    const int b  = bh >> 4;

    __shared__ float Qt[64][68];  // [d][qrow]
    __shared__ float Kt[64][68];  // [d][key]
    __shared__ float Vs[64][68];  // [key][d]
    __shared__ float Ss[64][69];  // [qrow][key] scores -> probs
    __shared__ float m_s[64], l_s[64], alpha_s[64];
    __shared__ int   mk[64];

    const int t  = threadIdx.x;
    const int ty = t >> 4, tx = t & 15;
    const int r0 = ty * 4, c0 = tx * 4;

    const int sr = t >> 2;          // staging row 0..63
    const int sc = (t & 3) * 16;    // staging col offset (16 elems/thread)

    {
        const bf16* src = q_ws + ((size_t)bh * S_ + (q0 + sr)) * DH_ + sc;
        #pragma unroll
        for (int j = 0; j < 16; j++) Qt[sc + j][sr] = 0.125f * b2f(src[j]);
    }
    if (t < 64) { m_s[t] = -1e30f; l_s[t] = 0.0f; }

    float o[4][4] = {};

    for (int kb0 = 0; kb0 < S_; kb0 += 64) {
        {
            const bf16* ksrc = k_ws + ((size_t)bh * S_ + (kb0 + sr)) * DH_ + sc;
            #pragma unroll
            for (int j = 0; j < 16; j++) Kt[sc + j][sr] = b2f(ksrc[j]);
            const bf16* vsrc = v_ws + ((size_t)bh * S_ + (kb0 + sr)) * DH_ + sc;
            #pragma unroll
            for (int j = 0; j < 16; j++) Vs[sr][sc + j] = b2f(vsrc[j]);
        }
        if (t < 64) mk[t] = mask[b * S_ + kb0 + t];
        __syncthreads();

        // S = (Q/8) K^T, 4x4 per thread
        float sc4[4][4] = {};
        for (int dd = 0; dd < 64; dd++) {
            float qa[4], ka[4];
            #pragma unroll
            for (int i = 0; i < 4; i++) qa[i] = Qt[dd][r0 + i];
            #pragma unroll
            for (int j = 0; j < 4; j++) ka[j] = Kt[dd][c0 + j];
            #pragma unroll
            for (int i = 0; i < 4; i++)
                #pragma unroll
                for (int j = 0; j < 4; j++)
                    sc4[i][j] = fmaf(qa[i], ka[j], sc4[i][j]);
        }
        #pragma unroll
        for (int j = 0; j < 4; j++) {
            const bool dead = (mk[c0 + j] == 0);
            #pragma unroll
            for (int i = 0; i < 4; i++)
                Ss[r0 + i][c0 + j] = dead ? -1e30f : sc4[i][j];
        }
        __syncthreads();

        // online-softmax row statistics (one thread per query row)
        if (t < 64) {
            const float mold = m_s[t];
            float mnew = mold;
            #pragma unroll 8
            for (int c = 0; c < 64; c++) mnew = fmaxf(mnew, Ss[t][c]);
            const float alpha = __expf(mold - mnew);
            float sum = 0.f;
            #pragma unroll 8
            for (int c = 0; c < 64; c++) {
                const float p = __expf(Ss[t][c] - mnew);
                Ss[t][c] = p;
                sum += p;
            }
            m_s[t]     = mnew;
            l_s[t]     = l_s[t] * alpha + sum;
            alpha_s[t] = alpha;
        }
        __syncthreads();

        // O = alpha*O + P V
        float al[4];
        #pragma unroll
        for (int i = 0; i < 4; i++) al[i] = alpha_s[r0 + i];
        #pragma unroll
        for (int i = 0; i < 4; i++)
            #pragma unroll
            for (int j = 0; j < 4; j++) o[i][j] *= al[i];
        for (int kk = 0; kk < 64; kk++) {
            float vv[4], pp[4];
            #pragma unroll
            for (int j = 0; j < 4; j++) vv[j] = Vs[kk][c0 + j];
            #pragma unroll
            for (int i = 0; i < 4; i++) pp[i] = Ss[r0 + i][kk];
            #pragma unroll
            for (int i = 0; i < 4; i++)
                #pragma unroll
                for (int j = 0; j < 4; j++)
                    o[i][j] = fmaf(pp[i], vv[j], o[i][j]);
        }
        __syncthreads();
    }

    const int h = bh & 15;
    #pragma unroll
    for (int i = 0; i < 4; i++) {
        const int r   = r0 + i;
        const float inv = 1.0f / l_s[r];
        bf16* dst = ctx + ((size_t)b * S_ + (q0 + r)) * D_ + h * DH_ + c0;
        #pragma unroll
        for (int j = 0; j < 4; j++) dst[j] = f2b(o[i][j] * inv);
    }
}

// ---------------------------------------------------------------------------
// Kernel 3: output projection. out = ctx @ Wo + bo. ctx bf16 ws, Wo/bo/out fp32.
// ---------------------------------------------------------------------------
__global__ __launch_bounds__(256) void proj_out_kernel(
    const bf16* __restrict__ Xc,
    const float* __restrict__ Wo, const float* __restrict__ bo,
    float* __restrict__ out)
{
    const int m0 = blockIdx.x * 64;
    const int n0 = blockIdx.y * 64;

    __shared__ float Xs[16][68];
    __shared__ float Ws[16][64];

    const int t  = threadIdx.x;
    const int ty = t >> 4, tx = t & 15;
    const int r0 = ty * 4, c0 = tx * 4;

    const int xr = t >> 2;
    const int xk = (t & 3) * 4;
    const int wk = t >> 4;
    const int wc = (t & 15) * 4;

    float acc[4][4] = {};

    for (int kb = 0; kb < D_; kb += 16) {
        {
            const bf16* src = Xc + (size_t)(m0 + xr) * D_ + kb + xk;
            #pragma unroll
            for (int j = 0; j < 4; j++) Xs[xk + j][xr] = b2f(src[j]);
        }
        {
            const float4 wv = *(const float4*)(Wo + (size_t)(kb + wk) * D_ + n0 + wc);
            Ws[wk][wc + 0] = wv.x;
            Ws[wk][wc + 1] = wv.y;
            Ws[wk][wc + 2] = wv.z;
            Ws[wk][wc + 3] = wv.w;
        }
        __syncthreads();
        #pragma unroll
        for (int kk = 0; kk < 16; kk++) {
            float a[4], bb[4];
            #pragma unroll
            for (int i = 0; i < 4; i++) a[i]  = Xs[kk][r0 + i];
            #pragma unroll
            for (int j = 0; j < 4; j++) bb[j] = Ws[kk][c0 + j];
            #pragma unroll
            for (int i = 0; i < 4; i++)
                #pragma unroll
                for (int j = 0; j < 4; j++)
                    acc[i][j] = fmaf(a[i], bb[j], acc[i][j]);
        }
        __syncthreads();
    }

    #pragma unroll
    for (int j = 0; j < 4; j++) {
        const int n = n0 + c0 + j;
        const float bv_ = bo[n];
        #pragma unroll
        for (int i = 0; i < 4; i++) {
            const int m = m0 + r0 + i;
            out[(size_t)m * D_ + n] = acc[i][j] + bv_;
        }
    }
}

// ---------------------------------------------------------------------------
extern "C" void kernel_launch(void* const* d_in, const int* in_sizes, int n_in,
                              void* d_out, int out_size, void* d_ws, size_t ws_size,
                              hipStream_t stream) {
    (void)in_sizes; (void)n_in; (void)out_size; (void)ws_size;

    const float* X    = (const float*)d_in[0];
    const int*   mask = (const int*)d_in[1];
    const float* Wq   = (const float*)d_in[2];
    const float* bq   = (const float*)d_in[3];
    const float* Wk   = (const float*)d_in[4];
    const float* bk   = (const float*)d_in[5];
    const float* Wv   = (const float*)d_in[6];
    const float* bv   = (const float*)d_in[7];
    const float* emo  = (const float*)d_in[8];
    const float* Wo   = (const float*)d_in[9];
    const float* bo   = (const float*)d_in[10];
    float* out = (float*)d_out;

    // workspace: q,k,v in [B,H,S,DH] bf16 (8 MB each) + ctx [B,S,D] bf16 (8 MB)
    bf16* q_ws = (bf16*)d_ws;
    bf16* k_ws = q_ws + (size_t)BS_ * D_;
    bf16* v_ws = k_ws + (size_t)BS_ * D_;
    bf16* ctx  = v_ws + (size_t)BS_ * D_;

    hipLaunchKernelGGL(proj_qkv_kernel, dim3(BS_ / 64, D_ / 64, 3), dim3(256), 0, stream,
                       X, Wq, bq, Wk, bk, Wv, bv, emo, q_ws, k_ws, v_ws);
    hipLaunchKernelGGL(attn_kernel, dim3(B_ * H_, S_ / 64), dim3(256), 0, stream,
                       q_ws, k_ws, v_ws, mask, ctx);
    hipLaunchKernelGGL(proj_out_kernel, dim3(BS_ / 64, D_ / 64), dim3(256), 0, stream,
                       ctx, Wo, bo, out);
}

// Round 3
// 657.348 us; speedup vs baseline: 1.9147x; 1.9147x over previous
//
#include <hip/hip_runtime.h>
#include <hip/hip_bf16.h>

// Problem: AdvancedAttentionLayer  B=2, S=2048, D=1024, H=16, DH=64
// Round 3: MFMA (bf16 16x16x32) flash attention; fp32 vector projections
// unchanged except: q pre-scaled by 1/8 at write, v written transposed
// [B,H,DH,S] so PV B-fragments are contiguous ds_read_b128.

#define B_  2
#define S_  2048
#define D_  1024
#define H_  16
#define DH_ 64
#define BS_ (B_*S_)

typedef __hip_bfloat16 bf16;
typedef __attribute__((ext_vector_type(8))) short s8v;   // 8 bf16 = 4 VGPRs
typedef __attribute__((ext_vector_type(4))) float f4v;   // MFMA C/D

__device__ __forceinline__ float b2f(bf16 x) { return __bfloat162float(x); }
__device__ __forceinline__ bf16  f2b(float x) { return __float2bfloat16(x); }

// ---------------------------------------------------------------------------
// Kernel 1: fused QKV projection (fp32 vector GEMM, unchanged core).
//   q: [B,H,S,DH], pre-scaled by 0.125, +bias +emotion
//   k: [B,H,S,DH]
//   v: [B,H,DH,S]  (TRANSPOSED for attn PV B-frags)
// ---------------------------------------------------------------------------
__global__ __launch_bounds__(256) void proj_qkv_kernel(
    const float* __restrict__ X,
    const float* __restrict__ Wq, const float* __restrict__ bq,
    const float* __restrict__ Wk, const float* __restrict__ bk,
    const float* __restrict__ Wv, const float* __restrict__ bv,
    const float* __restrict__ emo,
    bf16* __restrict__ q_ws, bf16* __restrict__ k_ws, bf16* __restrict__ v_ws)
{
    const int m0 = blockIdx.x * 64;
    const int n0 = blockIdx.y * 64;
    const int z  = blockIdx.z;

    const float* __restrict__ W    = (z == 0) ? Wq : (z == 1) ? Wk : Wv;
    const float* __restrict__ bias = (z == 0) ? bq : (z == 1) ? bk : bv;

    __shared__ float Xs[16][68];
    __shared__ float Ws[16][64];

    const int t  = threadIdx.x;
    const int ty = t >> 4, tx = t & 15;
    const int r0 = ty * 4, c0 = tx * 4;

    const int xr = t >> 2;
    const int xk = (t & 3) * 4;
    const int wk = t >> 4;
    const int wc = (t & 15) * 4;

    float acc[4][4] = {};

    for (int kb = 0; kb < D_; kb += 16) {
        {
            const float4 xv = *(const float4*)(X + (size_t)(m0 + xr) * D_ + kb + xk);
            Xs[xk + 0][xr] = xv.x;
            Xs[xk + 1][xr] = xv.y;
            Xs[xk + 2][xr] = xv.z;
            Xs[xk + 3][xr] = xv.w;
        }
        {
            const float4 wv = *(const float4*)(W + (size_t)(kb + wk) * D_ + n0 + wc);
            Ws[wk][wc + 0] = wv.x;
            Ws[wk][wc + 1] = wv.y;
            Ws[wk][wc + 2] = wv.z;
            Ws[wk][wc + 3] = wv.w;
        }
        __syncthreads();
        #pragma unroll
        for (int kk = 0; kk < 16; kk++) {
            float a[4], bb[4];
            #pragma unroll
            for (int i = 0; i < 4; i++) a[i]  = Xs[kk][r0 + i];
            #pragma unroll
            for (int j = 0; j < 4; j++) bb[j] = Ws[kk][c0 + j];
            #pragma unroll
            for (int i = 0; i < 4; i++)
                #pragma unroll
                for (int j = 0; j < 4; j++)
                    acc[i][j] = fmaf(a[i], bb[j], acc[i][j]);
        }
        __syncthreads();
    }

    const int h = n0 >> 6;   // one head per n-tile
    #pragma unroll
    for (int j = 0; j < 4; j++) {
        const int n   = n0 + c0 + j;
        const int dh  = n & 63;
        const float bv_ = bias[n];
        #pragma unroll
        for (int i = 0; i < 4; i++) {
            const int m = m0 + r0 + i;
            const int b = m >> 11, s = m & 2047;
            const int bh = b * H_ + h;
            if (z == 0) {
                const float y = (acc[i][j] + bv_ + emo[n]) * 0.125f;
                q_ws[(((size_t)bh * S_) + s) * DH_ + dh] = f2b(y);
            } else if (z == 1) {
                k_ws[(((size_t)bh * S_) + s) * DH_ + dh] = f2b(acc[i][j] + bv_);
            } else {
                v_ws[(((size_t)bh * DH_) + dh) * S_ + s] = f2b(acc[i][j] + bv_);
            }
        }
    }
}

// ---------------------------------------------------------------------------
// Kernel 2: MFMA flash attention.
// Grid: (B*H, S/64)  Block: 256 = 4 waves; each wave owns 16 q-rows.
// mfma_f32_16x16x32_bf16 layouts (HW-verified, m89/m120):
//   A[m][k]: m = lane&15, k = (lane>>4)*8 + j   (j=0..7, contiguous)
//   B[k][n]: n = lane&15, k = (lane>>4)*8 + j
//   C/D    : col = lane&15, row = (lane>>4)*4 + reg
// ---------------------------------------------------------------------------
#define PAD_ 72   // LDS row stride in bf16 elems: +8 pad -> 2-way max aliasing

__global__ __launch_bounds__(256) void attn_kernel(
    const bf16* __restrict__ q_ws, const bf16* __restrict__ k_ws,
    const bf16* __restrict__ v_ws, const int* __restrict__ mask,
    bf16* __restrict__ ctx)
{
    const int bh = blockIdx.x;           // b*H + h
    const int q0 = blockIdx.y * 64;
    const int b  = bh >> 4;
    const int h  = bh & 15;

    __shared__ bf16 q_lds[64 * PAD_];    // [qrow][d]
    __shared__ bf16 k_lds[64 * PAD_];    // [key][d]
    __shared__ bf16 vt_lds[64 * PAD_];   // [d][key]
    __shared__ bf16 p_lds[4][16 * PAD_]; // per-wave [row][key]
    __shared__ float mk_lds[64];

    const int t    = threadIdx.x;
    const int wave = t >> 6;
    const int lane = t & 63;
    const int quad = lane >> 4;
    const int l15  = lane & 15;

    // staging indices: 256 threads x 32B each per 64x64 bf16 tile
    const int srow = t >> 2;             // 0..63
    const int soff = (t & 3) * 16;       // 0/16/32/48 elems

    // ---- stage Q (once) ----
    {
        const bf16* src = q_ws + ((size_t)bh * S_ + q0 + srow) * DH_ + soff;
        *(s8v*)&q_lds[srow * PAD_ + soff]     = *(const s8v*)src;
        *(s8v*)&q_lds[srow * PAD_ + soff + 8] = *(const s8v*)(src + 8);
    }
    __syncthreads();

    // ---- Q A-frags (loop-invariant): rows wave*16 + l15, d-halves dt ----
    s8v aq[2];
    #pragma unroll
    for (int dt = 0; dt < 2; dt++)
        aq[dt] = *(const s8v*)&q_lds[(wave * 16 + l15) * PAD_ + dt * 32 + quad * 8];

    f4v oacc[4] = {};                    // O[16q][64d], C-layout, 4 n-tiles
    float m_run[4], l_run[4];
    #pragma unroll
    for (int r = 0; r < 4; r++) { m_run[r] = -1e30f; l_run[r] = 0.0f; }

    for (int kb0 = 0; kb0 < S_; kb0 += 64) {
        // ---- stage K, Vt, mask ----
        {
            const bf16* ks = k_ws + ((size_t)bh * S_ + kb0 + srow) * DH_ + soff;
            *(s8v*)&k_lds[srow * PAD_ + soff]     = *(const s8v*)ks;
            *(s8v*)&k_lds[srow * PAD_ + soff + 8] = *(const s8v*)(ks + 8);
            const bf16* vs = v_ws + ((size_t)bh * DH_ + srow) * S_ + kb0 + soff;
            *(s8v*)&vt_lds[srow * PAD_ + soff]     = *(const s8v*)vs;
            *(s8v*)&vt_lds[srow * PAD_ + soff + 8] = *(const s8v*)(vs + 8);
        }
        if (t < 64) mk_lds[t] = (float)mask[b * S_ + kb0 + t];
        __syncthreads();

        // ---- S = Q K^T : 4 key-tiles x 2 d-halves ----
        f4v sacc[4] = {};
        #pragma unroll
        for (int kt = 0; kt < 4; kt++) {
            #pragma unroll
            for (int dt = 0; dt < 2; dt++) {
                const s8v bk_ = *(const s8v*)&k_lds[(kt * 16 + l15) * PAD_ + dt * 32 + quad * 8];
                sacc[kt] = __builtin_amdgcn_mfma_f32_16x16x32_bf16(aq[dt], bk_, sacc[kt], 0, 0, 0);
            }
        }

        // ---- online softmax, register-resident ----
        float fm[4];
        #pragma unroll
        for (int kt = 0; kt < 4; kt++) fm[kt] = mk_lds[kt * 16 + l15];

        float p[4][4];                   // [kt][r]
        #pragma unroll
        for (int r = 0; r < 4; r++) {
            float bm = fmaxf(fmaxf(sacc[0][r], sacc[1][r]), fmaxf(sacc[2][r], sacc[3][r]));
            bm = fmaxf(bm, __shfl_xor(bm, 1));
            bm = fmaxf(bm, __shfl_xor(bm, 2));
            bm = fmaxf(bm, __shfl_xor(bm, 4));
            bm = fmaxf(bm, __shfl_xor(bm, 8));
            const float mnew = fmaxf(m_run[r], bm);
            float rs = 0.0f;
            #pragma unroll
            for (int kt = 0; kt < 4; kt++) {
                const float pv = __expf(sacc[kt][r] - mnew) * fm[kt];
                p[kt][r] = pv;
                rs += pv;
            }
            rs += __shfl_xor(rs, 1);
            rs += __shfl_xor(rs, 2);
            rs += __shfl_xor(rs, 4);
            rs += __shfl_xor(rs, 8);
            const float alpha = __expf(m_run[r] - mnew);
            l_run[r] = l_run[r] * alpha + rs;
            m_run[r] = mnew;
            // rescale O row r
            #pragma unroll
            for (int nt = 0; nt < 4; nt++) oacc[nt][r] *= alpha;
        }

        // ---- P (C-layout fp32) -> LDS bf16 ----
        #pragma unroll
        for (int kt = 0; kt < 4; kt++)
            #pragma unroll
            for (int r = 0; r < 4; r++)
                p_lds[wave][(quad * 4 + r) * PAD_ + kt * 16 + l15] = f2b(p[kt][r]);
        __syncthreads();   // own-wave LDS write->read ordering (and wg-wide)

        // ---- O += P V : 2 key-halves x 4 d-tiles ----
        #pragma unroll
        for (int kh = 0; kh < 2; kh++) {
            const s8v ap = *(const s8v*)&p_lds[wave][l15 * PAD_ + kh * 32 + quad * 8];
            #pragma unroll
            for (int nt = 0; nt < 4; nt++) {
                const s8v bv_ = *(const s8v*)&vt_lds[(nt * 16 + l15) * PAD_ + kh * 32 + quad * 8];
                oacc[nt] = __builtin_amdgcn_mfma_f32_16x16x32_bf16(ap, bv_, oacc[nt], 0, 0, 0);
            }
        }
        __syncthreads();   // K/Vt reuse barrier before next staging
    }

    // ---- epilogue: O / l -> ctx [B,S,D] bf16 ----
    float invl[4];
    #pragma unroll
    for (int r = 0; r < 4; r++) invl[r] = 1.0f / l_run[r];
    #pragma unroll
    for (int nt = 0; nt < 4; nt++) {
        #pragma unroll
        for (int r = 0; r < 4; r++) {
            const int q = q0 + wave * 16 + quad * 4 + r;
            ctx[((size_t)b * S_ + q) * D_ + h * DH_ + nt * 16 + l15] = f2b(oacc[nt][r] * invl[r]);
        }
    }
}

// ---------------------------------------------------------------------------
// Kernel 3: output projection (unchanged). out = ctx @ Wo + bo, fp32 out.
// ---------------------------------------------------------------------------
__global__ __launch_bounds__(256) void proj_out_kernel(
    const bf16* __restrict__ Xc,
    const float* __restrict__ Wo, const float* __restrict__ bo,
    float* __restrict__ out)
{
    const int m0 = blockIdx.x * 64;
    const int n0 = blockIdx.y * 64;

    __shared__ float Xs[16][68];
    __shared__ float Ws[16][64];

    const int t  = threadIdx.x;
    const int ty = t >> 4, tx = t & 15;
    const int r0 = ty * 4, c0 = tx * 4;

    const int xr = t >> 2;
    const int xk = (t & 3) * 4;
    const int wk = t >> 4;
    const int wc = (t & 15) * 4;

    float acc[4][4] = {};

    for (int kb = 0; kb < D_; kb += 16) {
        {
            const bf16* src = Xc + (size_t)(m0 + xr) * D_ + kb + xk;
            #pragma unroll
            for (int j = 0; j < 4; j++) Xs[xk + j][xr] = b2f(src[j]);
        }
        {
            const float4 wv = *(const float4*)(Wo + (size_t)(kb + wk) * D_ + n0 + wc);
            Ws[wk][wc + 0] = wv.x;
            Ws[wk][wc + 1] = wv.y;
            Ws[wk][wc + 2] = wv.z;
            Ws[wk][wc + 3] = wv.w;
        }
        __syncthreads();
        #pragma unroll
        for (int kk = 0; kk < 16; kk++) {
            float a[4], bb[4];
            #pragma unroll
            for (int i = 0; i < 4; i++) a[i]  = Xs[kk][r0 + i];
            #pragma unroll
            for (int j = 0; j < 4; j++) bb[j] = Ws[kk][c0 + j];
            #pragma unroll
            for (int i = 0; i < 4; i++)
                #pragma unroll
                for (int j = 0; j < 4; j++)
                    acc[i][j] = fmaf(a[i], bb[j], acc[i][j]);
        }
        __syncthreads();
    }

    #pragma unroll
    for (int j = 0; j < 4; j++) {
        const int n = n0 + c0 + j;
        const float bv_ = bo[n];
        #pragma unroll
        for (int i = 0; i < 4; i++) {
            const int m = m0 + r0 + i;
            out[(size_t)m * D_ + n] = acc[i][j] + bv_;
        }
    }
}

// ---------------------------------------------------------------------------
extern "C" void kernel_launch(void* const* d_in, const int* in_sizes, int n_in,
                              void* d_out, int out_size, void* d_ws, size_t ws_size,
                              hipStream_t stream) {
    (void)in_sizes; (void)n_in; (void)out_size; (void)ws_size;

    const float* X    = (const float*)d_in[0];
    const int*   mask = (const int*)d_in[1];
    const float* Wq   = (const float*)d_in[2];
    const float* bq   = (const float*)d_in[3];
    const float* Wk   = (const float*)d_in[4];
    const float* bk   = (const float*)d_in[5];
    const float* Wv   = (const float*)d_in[6];
    const float* bv   = (const float*)d_in[7];
    const float* emo  = (const float*)d_in[8];
    const float* Wo   = (const float*)d_in[9];
    const float* bo   = (const float*)d_in[10];
    float* out = (float*)d_out;

    bf16* q_ws = (bf16*)d_ws;                       // [B,H,S,DH]
    bf16* k_ws = q_ws + (size_t)BS_ * D_;           // [B,H,S,DH]
    bf16* v_ws = k_ws + (size_t)BS_ * D_;           // [B,H,DH,S]
    bf16* ctx  = v_ws + (size_t)BS_ * D_;           // [B,S,D]

    hipLaunchKernelGGL(proj_qkv_kernel, dim3(BS_ / 64, D_ / 64, 3), dim3(256), 0, stream,
                       X, Wq, bq, Wk, bk, Wv, bv, emo, q_ws, k_ws, v_ws);
    hipLaunchKernelGGL(attn_kernel, dim3(B_ * H_, S_ / 64), dim3(256), 0, stream,
                       q_ws, k_ws, v_ws, mask, ctx);
    hipLaunchKernelGGL(proj_out_kernel, dim3(BS_ / 64, D_ / 64), dim3(256), 0, stream,
                       ctx, Wo, bo, out);
}

// Round 4
// 283.948 us; speedup vs baseline: 4.4325x; 2.3150x over previous
//
#include <hip/hip_runtime.h>
#include <hip/hip_bf16.h>

// Problem: AdvancedAttentionLayer  B=2, S=2048, D=1024, H=16, DH=64
// Round 4: all three projections -> bf16 MFMA GEMM (m97 structure:
// global_load_lds width=16, 128x128 tile, BK=64, 4 waves x 4x4 acc).
// Prep kernels convert X->bf16 and W->W^T bf16. V-projection computes
// C^T via MFMA operand swap so the [B,H,DH,S] store is coalesced.
// Attn kernel unchanged from round 3.

#define B_  2
#define S_  2048
#define D_  1024
#define K_  1024
#define H_  16
#define DH_ 64
#define BS_ (B_*S_)

typedef __hip_bfloat16 bf16;
typedef __attribute__((ext_vector_type(8))) short s8v;   // 8 bf16 = 4 VGPRs
typedef __attribute__((ext_vector_type(4))) short s4v;   // 4 bf16
typedef __attribute__((ext_vector_type(4))) float f4v;   // MFMA C/D

__device__ __forceinline__ float b2f(bf16 x) { return __bfloat162float(x); }
__device__ __forceinline__ bf16  f2b(float x) { return __float2bfloat16(x); }

__device__ __forceinline__ void gl_lds_16B(const bf16* g, bf16* l) {
    __builtin_amdgcn_global_load_lds(
        (const __attribute__((address_space(1))) unsigned int*)g,
        (__attribute__((address_space(3))) unsigned int*)l, 16, 0, 0);
}

// ---------------------------------------------------------------------------
// Prep 1: X fp32 -> bf16 (same layout [4096][1024])
// ---------------------------------------------------------------------------
__global__ __launch_bounds__(256) void convert_x_kernel(
    const float* __restrict__ X, bf16* __restrict__ Xb)
{
    const size_t idx = ((size_t)blockIdx.x * 256 + threadIdx.x) * 4;
    const float4 v = *(const float4*)(X + idx);
    s4v o;
    o[0] = *(short*)&(bf16&)*(bf16[]){f2b(v.x)};  // avoid UB: do it simply below
    bf16 tmp0 = f2b(v.x), tmp1 = f2b(v.y), tmp2 = f2b(v.z), tmp3 = f2b(v.w);
    o[0] = *(short*)&tmp0; o[1] = *(short*)&tmp1;
    o[2] = *(short*)&tmp2; o[3] = *(short*)&tmp3;
    *(s4v*)(Xb + idx) = o;
}

// ---------------------------------------------------------------------------
// Prep 2: W [K][N] fp32 -> WT [N][K] bf16, 64x64 LDS tiles. z picks weight.
// ---------------------------------------------------------------------------
__global__ __launch_bounds__(256) void transpose_w_kernel(
    const float* __restrict__ Wq, const float* __restrict__ Wk,
    const float* __restrict__ Wv, const float* __restrict__ Wo,
    bf16* __restrict__ WTq, bf16* __restrict__ WTk,
    bf16* __restrict__ WTv, bf16* __restrict__ WTo)
{
    const int z = blockIdx.z;
    const float* __restrict__ W = (z == 0) ? Wq : (z == 1) ? Wk : (z == 2) ? Wv : Wo;
    bf16* __restrict__ WT       = (z == 0) ? WTq : (z == 1) ? WTk : (z == 2) ? WTv : WTo;

    const int k0 = blockIdx.x * 64;
    const int n0 = blockIdx.y * 64;

    __shared__ float Ls[64][68];

    const int t  = threadIdx.x;
    const int lr = t >> 4;          // 0..15
    const int lc = (t & 15) * 4;    // 0..60

    #pragma unroll
    for (int i = 0; i < 4; i++) {
        const int k = i * 16 + lr;
        const float4 v = *(const float4*)(W + (size_t)(k0 + k) * K_ + n0 + lc);
        Ls[k][lc + 0] = v.x; Ls[k][lc + 1] = v.y;
        Ls[k][lc + 2] = v.z; Ls[k][lc + 3] = v.w;
    }
    __syncthreads();
    #pragma unroll
    for (int i = 0; i < 4; i++) {
        const int n = i * 16 + lr;
        s4v o;
        #pragma unroll
        for (int j = 0; j < 4; j++) {
            bf16 tb = f2b(Ls[lc + j][n]);
            o[j] = *(short*)&tb;
        }
        *(s4v*)(WT + (size_t)(n0 + n) * K_ + k0 + lc) = o;
    }
}

// ---------------------------------------------------------------------------
// Shared MFMA GEMM core: C(128x128) = A[M=4096][K] x BT[N][K]^T.
// SWAPPED=true computes the transposed C/D layout (operands swapped).
// ---------------------------------------------------------------------------
template <bool SWAPPED>
__device__ __forceinline__ void gemm_tile(
    const bf16* __restrict__ A, const bf16* __restrict__ BT,
    int m0, int n0, bf16* As, bf16* Bs, f4v acc[4][4])
{
    const int t    = threadIdx.x;
    const int lane = t & 63;
    const int wave = t >> 6;
    const int quad = lane >> 4;
    const int l15  = lane & 15;
    const int wr   = wave >> 1;     // wave row (2x2 wave grid)
    const int wc   = wave & 1;

    const int sr = t >> 3;          // staging row 0..31 (per issue)
    const int sc = (t & 7) * 8;     // staging col elems

    for (int kb = 0; kb < K_; kb += 64) {
        #pragma unroll
        for (int i = 0; i < 4; i++) {
            const int r = i * 32 + sr;
            gl_lds_16B(A  + (size_t)(m0 + r) * K_ + kb + sc, As + r * 64 + sc);
            gl_lds_16B(BT + (size_t)(n0 + r) * K_ + kb + sc, Bs + r * 64 + sc);
        }
        __syncthreads();   // drains vmcnt (global_load_lds) + barrier

        #pragma unroll
        for (int ks = 0; ks < 2; ks++) {
            s8v fA[4], fB[4];
            #pragma unroll
            for (int i = 0; i < 4; i++) {
                fA[i] = *(const s8v*)&As[(wr * 64 + i * 16 + l15) * 64 + ks * 32 + quad * 8];
                fB[i] = *(const s8v*)&Bs[(wc * 64 + i * 16 + l15) * 64 + ks * 32 + quad * 8];
            }
            #pragma unroll
            for (int i = 0; i < 4; i++)
                #pragma unroll
                for (int j = 0; j < 4; j++)
                    acc[i][j] = SWAPPED
                        ? __builtin_amdgcn_mfma_f32_16x16x32_bf16(fB[i], fA[j], acc[i][j], 0, 0, 0)
                        : __builtin_amdgcn_mfma_f32_16x16x32_bf16(fA[i], fB[j], acc[i][j], 0, 0, 0);
        }
        __syncthreads();
    }
}

// ---------------------------------------------------------------------------
// Kernel: QKV projection via MFMA. Grid (32, 8, 3), block 256.
//   z=0: q_ws[B,H,S,DH] = (X Wq + bq + emo) * 0.125
//   z=1: k_ws[B,H,S,DH] =  X Wk + bk
//   z=2: v_ws[B,H,DH,S] = (X Wv + bv)^T   (operand-swapped MFMA)
// ---------------------------------------------------------------------------
__global__ __launch_bounds__(256) void proj_qkv_kernel(
    const bf16* __restrict__ Xb,
    const bf16* __restrict__ WTq, const float* __restrict__ bq,
    const bf16* __restrict__ WTk, const float* __restrict__ bk,
    const bf16* __restrict__ WTv, const float* __restrict__ bv,
    const float* __restrict__ emo,
    bf16* __restrict__ q_ws, bf16* __restrict__ k_ws, bf16* __restrict__ v_ws)
{
    const int m0 = blockIdx.x * 128;
    const int n0 = blockIdx.y * 128;
    const int z  = blockIdx.z;

    __shared__ __align__(16) bf16 As[128 * 64];
    __shared__ __align__(16) bf16 Bs[128 * 64];

    const int t    = threadIdx.x;
    const int lane = t & 63;
    const int wave = t >> 6;
    const int quad = lane >> 4;
    const int l15  = lane & 15;
    const int wr   = wave >> 1;
    const int wc   = wave & 1;

    f4v acc[4][4] = {};

    if (z == 0) {
        gemm_tile<false>(Xb, WTq, m0, n0, As, Bs, acc);
        #pragma unroll
        for (int j = 0; j < 4; j++) {
            const int n  = n0 + wc * 64 + j * 16 + l15;
            const int h  = n >> 6, dh = n & 63;
            const float bias_n = bq[n] + emo[n];
            #pragma unroll
            for (int i = 0; i < 4; i++) {
                #pragma unroll
                for (int r = 0; r < 4; r++) {
                    const int m = m0 + wr * 64 + i * 16 + quad * 4 + r;
                    const int b = m >> 11, s = m & 2047;
                    q_ws[(((size_t)(b * H_ + h)) * S_ + s) * DH_ + dh] =
                        f2b((acc[i][j][r] + bias_n) * 0.125f);
                }
            }
        }
    } else if (z == 1) {
        gemm_tile<false>(Xb, WTk, m0, n0, As, Bs, acc);
        #pragma unroll
        for (int j = 0; j < 4; j++) {
            const int n  = n0 + wc * 64 + j * 16 + l15;
            const int h  = n >> 6, dh = n & 63;
            const float bias_n = bk[n];
            #pragma unroll
            for (int i = 0; i < 4; i++) {
                #pragma unroll
                for (int r = 0; r < 4; r++) {
                    const int m = m0 + wr * 64 + i * 16 + quad * 4 + r;
                    const int b = m >> 11, s = m & 2047;
                    k_ws[(((size_t)(b * H_ + h)) * S_ + s) * DH_ + dh] =
                        f2b(acc[i][j][r] + bias_n);
                }
            }
        }
    } else {
        gemm_tile<true>(Xb, WTv, m0, n0, As, Bs, acc);
        // acc[i][j]: i = n-tile, j = m-tile; C/D row=quad*4+r -> n, col=l15 -> m
        #pragma unroll
        for (int j = 0; j < 4; j++) {
            const int m = m0 + wr * 64 + j * 16 + l15;
            const int b = m >> 11, s = m & 2047;
            #pragma unroll
            for (int i = 0; i < 4; i++) {
                #pragma unroll
                for (int r = 0; r < 4; r++) {
                    const int n  = n0 + wc * 64 + i * 16 + quad * 4 + r;
                    const int h  = n >> 6, dh = n & 63;
                    v_ws[(((size_t)(b * H_ + h)) * DH_ + dh) * S_ + s] =
                        f2b(acc[i][j][r] + bv[n]);
                }
            }
        }
    }
}

// ---------------------------------------------------------------------------
// Kernel: output projection via MFMA. out = ctx @ Wo + bo, fp32 out [4096][1024].
// ---------------------------------------------------------------------------
__global__ __launch_bounds__(256) void proj_out_kernel(
    const bf16* __restrict__ ctx, const bf16* __restrict__ WTo,
    const float* __restrict__ bo, float* __restrict__ out)
{
    const int m0 = blockIdx.x * 128;
    const int n0 = blockIdx.y * 128;

    __shared__ __align__(16) bf16 As[128 * 64];
    __shared__ __align__(16) bf16 Bs[128 * 64];

    const int t    = threadIdx.x;
    const int lane = t & 63;
    const int wave = t >> 6;
    const int quad = lane >> 4;
    const int l15  = lane & 15;
    const int wr   = wave >> 1;
    const int wc   = wave & 1;

    f4v acc[4][4] = {};
    gemm_tile<false>(ctx, WTo, m0, n0, As, Bs, acc);

    #pragma unroll
    for (int j = 0; j < 4; j++) {
        const int n = n0 + wc * 64 + j * 16 + l15;
        const float bias_n = bo[n];
        #pragma unroll
        for (int i = 0; i < 4; i++) {
            #pragma unroll
            for (int r = 0; r < 4; r++) {
                const int m = m0 + wr * 64 + i * 16 + quad * 4 + r;
                out[(size_t)m * D_ + n] = acc[i][j][r] + bias_n;
            }
        }
    }
}

// ---------------------------------------------------------------------------
// Kernel: MFMA flash attention (unchanged from round 3).
// ---------------------------------------------------------------------------
#define PAD_ 72

__global__ __launch_bounds__(256) void attn_kernel(
    const bf16* __restrict__ q_ws, const bf16* __restrict__ k_ws,
    const bf16* __restrict__ v_ws, const int* __restrict__ mask,
    bf16* __restrict__ ctx)
{
    const int bh = blockIdx.x;
    const int q0 = blockIdx.y * 64;
    const int b  = bh >> 4;
    const int h  = bh & 15;

    __shared__ bf16 q_lds[64 * PAD_];
    __shared__ bf16 k_lds[64 * PAD_];
    __shared__ bf16 vt_lds[64 * PAD_];
    __shared__ bf16 p_lds[4][16 * PAD_];
    __shared__ float mk_lds[64];

    const int t    = threadIdx.x;
    const int wave = t >> 6;
    const int lane = t & 63;
    const int quad = lane >> 4;
    const int l15  = lane & 15;

    const int srow = t >> 2;
    const int soff = (t & 3) * 16;

    {
        const bf16* src = q_ws + ((size_t)bh * S_ + q0 + srow) * DH_ + soff;
        *(s8v*)&q_lds[srow * PAD_ + soff]     = *(const s8v*)src;
        *(s8v*)&q_lds[srow * PAD_ + soff + 8] = *(const s8v*)(src + 8);
    }
    __syncthreads();

    s8v aq[2];
    #pragma unroll
    for (int dt = 0; dt < 2; dt++)
        aq[dt] = *(const s8v*)&q_lds[(wave * 16 + l15) * PAD_ + dt * 32 + quad * 8];

    f4v oacc[4] = {};
    float m_run[4], l_run[4];
    #pragma unroll
    for (int r = 0; r < 4; r++) { m_run[r] = -1e30f; l_run[r] = 0.0f; }

    for (int kb0 = 0; kb0 < S_; kb0 += 64) {
        {
            const bf16* ks = k_ws + ((size_t)bh * S_ + kb0 + srow) * DH_ + soff;
            *(s8v*)&k_lds[srow * PAD_ + soff]     = *(const s8v*)ks;
            *(s8v*)&k_lds[srow * PAD_ + soff + 8] = *(const s8v*)(ks + 8);
            const bf16* vs = v_ws + ((size_t)bh * DH_ + srow) * S_ + kb0 + soff;
            *(s8v*)&vt_lds[srow * PAD_ + soff]     = *(const s8v*)vs;
            *(s8v*)&vt_lds[srow * PAD_ + soff + 8] = *(const s8v*)(vs + 8);
        }
        if (t < 64) mk_lds[t] = (float)mask[b * S_ + kb0 + t];
        __syncthreads();

        f4v sacc[4] = {};
        #pragma unroll
        for (int kt = 0; kt < 4; kt++) {
            #pragma unroll
            for (int dt = 0; dt < 2; dt++) {
                const s8v bk_ = *(const s8v*)&k_lds[(kt * 16 + l15) * PAD_ + dt * 32 + quad * 8];
                sacc[kt] = __builtin_amdgcn_mfma_f32_16x16x32_bf16(aq[dt], bk_, sacc[kt], 0, 0, 0);
            }
        }

        float fm[4];
        #pragma unroll
        for (int kt = 0; kt < 4; kt++) fm[kt] = mk_lds[kt * 16 + l15];

        float p[4][4];
        #pragma unroll
        for (int r = 0; r < 4; r++) {
            float bm = fmaxf(fmaxf(sacc[0][r], sacc[1][r]), fmaxf(sacc[2][r], sacc[3][r]));
            bm = fmaxf(bm, __shfl_xor(bm, 1));
            bm = fmaxf(bm, __shfl_xor(bm, 2));
            bm = fmaxf(bm, __shfl_xor(bm, 4));
            bm = fmaxf(bm, __shfl_xor(bm, 8));
            const float mnew = fmaxf(m_run[r], bm);
            float rs = 0.0f;
            #pragma unroll
            for (int kt = 0; kt < 4; kt++) {
                const float pv = __expf(sacc[kt][r] - mnew) * fm[kt];
                p[kt][r] = pv;
                rs += pv;
            }
            rs += __shfl_xor(rs, 1);
            rs += __shfl_xor(rs, 2);
            rs += __shfl_xor(rs, 4);
            rs += __shfl_xor(rs, 8);
            const float alpha = __expf(m_run[r] - mnew);
            l_run[r] = l_run[r] * alpha + rs;
            m_run[r] = mnew;
            #pragma unroll
            for (int nt = 0; nt < 4; nt++) oacc[nt][r] *= alpha;
        }

        #pragma unroll
        for (int kt = 0; kt < 4; kt++)
            #pragma unroll
            for (int r = 0; r < 4; r++)
                p_lds[wave][(quad * 4 + r) * PAD_ + kt * 16 + l15] = f2b(p[kt][r]);
        __syncthreads();

        #pragma unroll
        for (int kh = 0; kh < 2; kh++) {
            const s8v ap = *(const s8v*)&p_lds[wave][l15 * PAD_ + kh * 32 + quad * 8];
            #pragma unroll
            for (int nt = 0; nt < 4; nt++) {
                const s8v bv_ = *(const s8v*)&vt_lds[(nt * 16 + l15) * PAD_ + kh * 32 + quad * 8];
                oacc[nt] = __builtin_amdgcn_mfma_f32_16x16x32_bf16(ap, bv_, oacc[nt], 0, 0, 0);
            }
        }
        __syncthreads();
    }

    float invl[4];
    #pragma unroll
    for (int r = 0; r < 4; r++) invl[r] = 1.0f / l_run[r];
    #pragma unroll
    for (int nt = 0; nt < 4; nt++) {
        #pragma unroll
        for (int r = 0; r < 4; r++) {
            const int q = q0 + wave * 16 + quad * 4 + r;
            ctx[((size_t)b * S_ + q) * D_ + h * DH_ + nt * 16 + l15] = f2b(oacc[nt][r] * invl[r]);
        }
    }
}

// ---------------------------------------------------------------------------
extern "C" void kernel_launch(void* const* d_in, const int* in_sizes, int n_in,
                              void* d_out, int out_size, void* d_ws, size_t ws_size,
                              hipStream_t stream) {
    (void)in_sizes; (void)n_in; (void)out_size; (void)ws_size;

    const float* X    = (const float*)d_in[0];
    const int*   mask = (const int*)d_in[1];
    const float* Wq   = (const float*)d_in[2];
    const float* bq   = (const float*)d_in[3];
    const float* Wk   = (const float*)d_in[4];
    const float* bk   = (const float*)d_in[5];
    const float* Wv   = (const float*)d_in[6];
    const float* bv   = (const float*)d_in[7];
    const float* emo  = (const float*)d_in[8];
    const float* Wo   = (const float*)d_in[9];
    const float* bo   = (const float*)d_in[10];
    float* out = (float*)d_out;

    bf16* q_ws = (bf16*)d_ws;                       // [B,H,S,DH]   8 MB
    bf16* k_ws = q_ws + (size_t)BS_ * D_;           // [B,H,S,DH]   8 MB
    bf16* v_ws = k_ws + (size_t)BS_ * D_;           // [B,H,DH,S]   8 MB
    bf16* ctx  = v_ws + (size_t)BS_ * D_;           // [B,S,D]      8 MB
    bf16* Xb   = ctx  + (size_t)BS_ * D_;           // [BS,D]       8 MB
    bf16* WTq  = Xb   + (size_t)BS_ * D_;           // [N,K]        2 MB
    bf16* WTk  = WTq  + (size_t)D_ * K_;
    bf16* WTv  = WTk  + (size_t)D_ * K_;
    bf16* WTo  = WTv  + (size_t)D_ * K_;

    hipLaunchKernelGGL(convert_x_kernel, dim3(BS_ * D_ / 1024), dim3(256), 0, stream, X, Xb);
    hipLaunchKernelGGL(transpose_w_kernel, dim3(K_ / 64, D_ / 64, 4), dim3(256), 0, stream,
                       Wq, Wk, Wv, Wo, WTq, WTk, WTv, WTo);
    hipLaunchKernelGGL(proj_qkv_kernel, dim3(BS_ / 128, D_ / 128, 3), dim3(256), 0, stream,
                       Xb, WTq, bq, WTk, bk, WTv, bv, emo, q_ws, k_ws, v_ws);
    hipLaunchKernelGGL(attn_kernel, dim3(B_ * H_, S_ / 64), dim3(256), 0, stream,
                       q_ws, k_ws, v_ws, mask, ctx);
    hipLaunchKernelGGL(proj_out_kernel, dim3(BS_ / 128, D_ / 128), dim3(256), 0, stream,
                       ctx, WTo, bo, out);
}